// Round 1
// baseline (213.033 us; speedup 1.0000x reference)
//
#include <hip/hip_runtime.h>
#include <hip/hip_bf16.h>
#include <math.h>

#define B 8
#define N 2048
#define F_IN 128
#define F_OUT 64
#define ALPHA 0.2f

// ---------------------------------------------------------------------------
// Kernel A: Wh = h @ W  (per-row), plus f = Wh·a1, g = Wh·a2
// One wave (64 lanes) per row; lane = output feature. 4 rows per 256-thr block.
// ---------------------------------------------------------------------------
__global__ __launch_bounds__(256) void wh_fg_kernel(
    const float* __restrict__ h, const float* __restrict__ W,
    const float* __restrict__ a, float* __restrict__ Wh,
    float* __restrict__ fv, float* __restrict__ gv)
{
    const int w    = threadIdx.x >> 6;   // wave id in block (0..3)
    const int lane = threadIdx.x & 63;   // feature index
    const int row  = blockIdx.x * 4 + w; // 0 .. B*N-1

    __shared__ float hs[4][F_IN];

    // stage h row into LDS: 64 lanes x float2 = 128 floats
    const float2* h2 = (const float2*)(h + (size_t)row * F_IN);
    float2 v = h2[lane];
    hs[w][2 * lane]     = v.x;
    hs[w][2 * lane + 1] = v.y;
    __syncthreads();

    float acc = 0.f;
#pragma unroll
    for (int k = 0; k < F_IN; ++k)
        acc += hs[w][k] * W[k * F_OUT + lane];   // wave reads 256B contiguous

    Wh[(size_t)row * F_OUT + lane] = acc;

    // f/g: dot with a1/a2 across the 64 lanes
    float fp = acc * a[lane];
    float gp = acc * a[F_OUT + lane];
#pragma unroll
    for (int off = 32; off >= 1; off >>= 1) {
        fp += __shfl_down(fp, off, 64);
        gp += __shfl_down(gp, off, 64);
    }
    if (lane == 0) {
        fv[row] = fp;
        gv[row] = gp;
    }
}

// ---------------------------------------------------------------------------
// Kernel B: per (b,i) row — compact neighbors, masked softmax, weighted sum.
// 256 threads per block.
// ---------------------------------------------------------------------------
__global__ __launch_bounds__(256) void attn_kernel(
    const float* __restrict__ adj, const float* __restrict__ Wh,
    const float* __restrict__ fv, const float* __restrict__ gv,
    float* __restrict__ out)
{
    const int i = blockIdx.x;      // target node
    const int b = blockIdx.y;      // batch
    const int tid  = threadIdx.x;
    const int lane = tid & 63;
    const int wid  = tid >> 6;

    __shared__ int   cnt;
    __shared__ unsigned short idxs[N];
    __shared__ float ps[N];
    __shared__ float red[8];
    __shared__ float accs[256];

    if (tid == 0) cnt = 0;
    __syncthreads();

    const float fi = fv[(size_t)b * N + i];
    const float* adjrow = adj + (size_t)i * N;
    const float* grow   = gv + (size_t)b * N;

    // Phase 1: compact neighbor list + per-thread max
    float lmax = -INFINITY;
    for (int j = tid; j < N; j += 256) {
        if (adjrow[j] > 0.f) {
            float s = fi + grow[j];
            s = (s > 0.f) ? s : ALPHA * s;   // leaky_relu
            int p = atomicAdd(&cnt, 1);
            idxs[p] = (unsigned short)j;
            ps[p]   = s;
            lmax = fmaxf(lmax, s);
        }
    }
    // block max reduction
#pragma unroll
    for (int off = 32; off >= 1; off >>= 1)
        lmax = fmaxf(lmax, __shfl_down(lmax, off, 64));
    if (lane == 0) red[wid] = lmax;
    __syncthreads();
    if (tid == 0)
        red[4] = fmaxf(fmaxf(red[0], red[1]), fmaxf(red[2], red[3]));
    __syncthreads();
    const float m = red[4];
    const int c = cnt;

    // Phase 2: exponentiate + denominator
    float lsum = 0.f;
    for (int p = tid; p < c; p += 256) {
        float e = __expf(ps[p] - m);
        ps[p] = e;
        lsum += e;
    }
#pragma unroll
    for (int off = 32; off >= 1; off >>= 1)
        lsum += __shfl_down(lsum, off, 64);
    if (lane == 0) red[wid] = lsum;
    __syncthreads();
    if (tid == 0)
        red[5] = red[0] + red[1] + red[2] + red[3];
    __syncthreads();
    const float inv = 1.0f / red[5];

    // Phase 3: weighted sum of Wh rows. thread = (chunk, feature)
    const int f     = tid & 63;   // feature
    const int chunk = tid >> 6;   // 0..3
    const float* WhB = Wh + (size_t)b * N * F_OUT;
    float acc = 0.f;
    for (int p = chunk; p < c; p += 4) {
        int j = idxs[p];
        acc += ps[p] * WhB[(size_t)j * F_OUT + f];  // wave reads 256B contiguous
    }
    accs[tid] = acc;
    __syncthreads();
    if (tid < 64) {
        float r = accs[tid] + accs[64 + tid] + accs[128 + tid] + accs[192 + tid];
        out[((size_t)b * N + i) * F_OUT + tid] = r * inv;
    }
}

extern "C" void kernel_launch(void* const* d_in, const int* in_sizes, int n_in,
                              void* d_out, int out_size, void* d_ws, size_t ws_size,
                              hipStream_t stream) {
    const float* h   = (const float*)d_in[0];
    const float* adj = (const float*)d_in[1];
    const float* W   = (const float*)d_in[2];
    const float* a   = (const float*)d_in[3];
    float* out = (float*)d_out;

    // workspace layout
    float* Wh = (float*)d_ws;                              // B*N*F_OUT = 4 MB
    float* fv = Wh + (size_t)B * N * F_OUT;                // 64 KB
    float* gv = fv + (size_t)B * N;                        // 64 KB

    dim3 gridA(B * N / 4);
    wh_fg_kernel<<<gridA, 256, 0, stream>>>(h, W, a, Wh, fv, gv);

    dim3 gridB(N, B);
    attn_kernel<<<gridB, 256, 0, stream>>>(adj, Wh, fv, gv, out);
}

// Round 2
// 148.732 us; speedup vs baseline: 1.4323x; 1.4323x over previous
//
#include <hip/hip_runtime.h>
#include <hip/hip_bf16.h>
#include <math.h>

#define B 8
#define N 2048
#define F_IN 128
#define F_OUT 64
#define ALPHA 0.2f
#define DEG_STRIDE 384   // max degree bound: mean 205.8, sigma 13.6 -> 13 sigma

// ---------------------------------------------------------------------------
// Kernel A: Wh = h @ W, f = Wh.a1, g = Wh.a2
// 256 threads = 4 waves; 16 rows/block (4 rows per wave, lane = out feature).
// W (32 KB) staged in LDS once per block.
// ---------------------------------------------------------------------------
__global__ __launch_bounds__(256) void wh_fg_kernel(
    const float* __restrict__ h, const float* __restrict__ W,
    const float* __restrict__ a, float* __restrict__ Wh,
    float* __restrict__ fv, float* __restrict__ gv)
{
    const int tid  = threadIdx.x;
    const int w    = tid >> 6;    // wave 0..3
    const int lane = tid & 63;    // feature

    __shared__ float Ws[F_IN * F_OUT];   // 32 KB, [k][f]
    __shared__ float hs[16 * F_IN];      // 8 KB,  [r][k]

    // stage W: 2048 float4, 8 per thread
    const float4* W4 = (const float4*)W;
    float4* Ws4 = (float4*)Ws;
#pragma unroll
    for (int q = 0; q < 8; ++q)
        Ws4[q * 256 + tid] = W4[q * 256 + tid];

    // stage 16 h rows: 512 float4, 2 per thread
    const float4* h4 = (const float4*)h;
    float4* hs4 = (float4*)hs;
    const size_t hbase = (size_t)blockIdx.x * 512;
#pragma unroll
    for (int q = 0; q < 2; ++q)
        hs4[q * 256 + tid] = h4[hbase + q * 256 + tid];

    const float av1 = a[lane];
    const float av2 = a[F_OUT + lane];
    __syncthreads();

    float acc[4] = {0.f, 0.f, 0.f, 0.f};
    const int lr0 = w * 4;  // first local row for this wave

    for (int k4 = 0; k4 < F_IN / 4; ++k4) {
        float4 hv[4];
#pragma unroll
        for (int rr = 0; rr < 4; ++rr)
            hv[rr] = hs4[(lr0 + rr) * (F_IN / 4) + k4];
#pragma unroll
        for (int kk = 0; kk < 4; ++kk) {
            float wv = Ws[(k4 * 4 + kk) * F_OUT + lane];
#pragma unroll
            for (int rr = 0; rr < 4; ++rr)
                acc[rr] += ((const float*)&hv[rr])[kk] * wv;
        }
    }

    const size_t row0 = (size_t)blockIdx.x * 16 + lr0;
#pragma unroll
    for (int rr = 0; rr < 4; ++rr) {
        Wh[(row0 + rr) * F_OUT + lane] = acc[rr];
        float fp = acc[rr] * av1;
        float gp = acc[rr] * av2;
#pragma unroll
        for (int off = 32; off >= 1; off >>= 1) {
            fp += __shfl_down(fp, off, 64);
            gp += __shfl_down(gp, off, 64);
        }
        if (lane == 0) {
            fv[row0 + rr] = fp;
            gv[row0 + rr] = gp;
        }
    }
}

// ---------------------------------------------------------------------------
// Kernel P: per-row neighbor compaction (batch-invariant, done once).
// ---------------------------------------------------------------------------
__global__ __launch_bounds__(256) void build_nbr(
    const float* __restrict__ adj, int* __restrict__ deg,
    unsigned short* __restrict__ idxg)
{
    const int i = blockIdx.x;
    const int tid = threadIdx.x;
    __shared__ int cnt;
    __shared__ unsigned short loc[DEG_STRIDE];

    if (tid == 0) cnt = 0;
    __syncthreads();

    const float* adjrow = adj + (size_t)i * N;
    for (int j = tid; j < N; j += 256) {
        if (adjrow[j] > 0.f) {
            int p = atomicAdd(&cnt, 1);
            loc[p] = (unsigned short)j;
        }
    }
    __syncthreads();
    const int c = cnt;
    if (tid == 0) deg[i] = c;
    unsigned short* dst = idxg + (size_t)i * DEG_STRIDE;
    for (int p = tid; p < c; p += 256)
        dst[p] = loc[p];
}

// ---------------------------------------------------------------------------
// Kernel B: per (b,i) masked softmax + weighted sum over compact neighbors.
// ---------------------------------------------------------------------------
__global__ __launch_bounds__(256) void attn_kernel(
    const float* __restrict__ Wh, const float* __restrict__ fv,
    const float* __restrict__ gv, const int* __restrict__ deg,
    const unsigned short* __restrict__ idxg, float* __restrict__ out)
{
    const int i = blockIdx.x;
    const int b = blockIdx.y;
    const int tid  = threadIdx.x;
    const int lane = tid & 63;
    const int wid  = tid >> 6;

    __shared__ unsigned short idxs[DEG_STRIDE];
    __shared__ float ps[DEG_STRIDE];
    __shared__ float red[8];
    __shared__ float accs[16 * F_OUT];   // [row_slot][feature]

    const int c = deg[i];
    const float fi = fv[(size_t)b * N + i];
    const float* grow = gv + (size_t)b * N;
    const unsigned short* src = idxg + (size_t)i * DEG_STRIDE;

    // Phase 1: scores + max
    float lmax = -INFINITY;
    for (int p = tid; p < c; p += 256) {
        int j = src[p];
        idxs[p] = (unsigned short)j;
        float s = fi + grow[j];
        s = (s > 0.f) ? s : ALPHA * s;
        ps[p] = s;
        lmax = fmaxf(lmax, s);
    }
#pragma unroll
    for (int off = 32; off >= 1; off >>= 1)
        lmax = fmaxf(lmax, __shfl_down(lmax, off, 64));
    if (lane == 0) red[wid] = lmax;
    __syncthreads();
    if (tid == 0)
        red[4] = fmaxf(fmaxf(red[0], red[1]), fmaxf(red[2], red[3]));
    __syncthreads();
    const float m = red[4];

    // Phase 2: exp + sum
    float lsum = 0.f;
    for (int p = tid; p < c; p += 256) {
        float e = __expf(ps[p] - m);
        ps[p] = e;
        lsum += e;
    }
#pragma unroll
    for (int off = 32; off >= 1; off >>= 1)
        lsum += __shfl_down(lsum, off, 64);
    if (lane == 0) red[wid] = lsum;
    __syncthreads();
    if (tid == 0)
        red[5] = red[0] + red[1] + red[2] + red[3];
    __syncthreads();
    const float inv = 1.0f / red[5];

    // Phase 3: weighted sum, thread = (row_slot ro 0..15, feature group sub 0..15)
    const int sub = tid & 15;   // 4 consecutive features = 16 B
    const int ro  = tid >> 4;   // row slot
    const float4* WhB4 = (const float4*)(Wh + (size_t)b * N * F_OUT);
    float4 acc = make_float4(0.f, 0.f, 0.f, 0.f);
    for (int p = ro; p < c; p += 16) {
        int j = idxs[p];
        float wgt = ps[p];
        float4 v = WhB4[(size_t)j * (F_OUT / 4) + sub];
        acc.x += wgt * v.x;
        acc.y += wgt * v.y;
        acc.z += wgt * v.z;
        acc.w += wgt * v.w;
    }
    ((float4*)accs)[ro * 16 + sub] = acc;
    __syncthreads();

    if (tid < F_OUT) {
        float r = 0.f;
#pragma unroll
        for (int rr = 0; rr < 16; ++rr)
            r += accs[rr * F_OUT + tid];
        out[((size_t)b * N + i) * F_OUT + tid] = r * inv;
    }
}

extern "C" void kernel_launch(void* const* d_in, const int* in_sizes, int n_in,
                              void* d_out, int out_size, void* d_ws, size_t ws_size,
                              hipStream_t stream) {
    const float* h   = (const float*)d_in[0];
    const float* adj = (const float*)d_in[1];
    const float* W   = (const float*)d_in[2];
    const float* a   = (const float*)d_in[3];
    float* out = (float*)d_out;

    // workspace layout
    char* ws = (char*)d_ws;
    float* Wh = (float*)ws;                                   // 4 MB
    float* fv = Wh + (size_t)B * N * F_OUT;                   // 64 KB
    float* gv = fv + (size_t)B * N;                           // 64 KB
    int*   deg = (int*)(gv + (size_t)B * N);                  // 8 KB
    unsigned short* idxg = (unsigned short*)(deg + N);        // 1.5 MB

    wh_fg_kernel<<<dim3(B * N / 16), 256, 0, stream>>>(h, W, a, Wh, fv, gv);
    build_nbr<<<dim3(N), 256, 0, stream>>>(adj, deg, idxg);
    attn_kernel<<<dim3(N, B), 256, 0, stream>>>(Wh, fv, gv, deg, idxg, out);
}

// Round 4
// 133.935 us; speedup vs baseline: 1.5906x; 1.1105x over previous
//
#include <hip/hip_runtime.h>
#include <hip/hip_bf16.h>
#include <math.h>

#define B 8
#define N 2048
#define F_IN 128
#define F_OUT 64
#define ALPHA 0.2f

typedef _Float16 half8 __attribute__((ext_vector_type(8)));
typedef _Float16 half2v __attribute__((ext_vector_type(2)));
typedef float f32x4 __attribute__((ext_vector_type(4)));

// ---------------------------------------------------------------------------
// Kernel 1: adj -> bitmask (u32 words). bits[i*64 + j/32] bit (j%32) = adj[i][j]>0
// ---------------------------------------------------------------------------
__global__ __launch_bounds__(256) void bitmask_kernel(
    const float* __restrict__ adj, unsigned* __restrict__ bits)
{
    const int i = blockIdx.x;
    const int tid = threadIdx.x;
    const int lane = tid & 63;
    const int w = tid >> 6;
    const float* row = adj + (size_t)i * N;
#pragma unroll
    for (int jt = 0; jt < 8; ++jt) {
        float v = row[jt * 256 + tid];
        unsigned long long m = __ballot(v > 0.f);
        if (lane == 0) {
            bits[i * 64 + jt * 8 + w * 2]     = (unsigned)m;
            bits[i * 64 + jt * 8 + w * 2 + 1] = (unsigned)(m >> 32);
        }
    }
}

// ---------------------------------------------------------------------------
// Kernel 2: WhT[b][f][j] (f16) = (h @ W)^T, plus f = Wh.a1, g = Wh.a2 (fp32)
// ---------------------------------------------------------------------------
__global__ __launch_bounds__(256) void wh_fg_t_kernel(
    const float* __restrict__ h, const float* __restrict__ W,
    const float* __restrict__ a, _Float16* __restrict__ WhT,
    float* __restrict__ fv, float* __restrict__ gv)
{
    const int tid  = threadIdx.x;
    const int w    = tid >> 6;
    const int lane = tid & 63;

    __shared__ float Ws[F_IN * F_OUT];    // 32 KB
    __shared__ float hs[16 * F_IN];       // 8 KB
    __shared__ float t32[16 * 65];        // transpose buffer (pad 65)

    const float4* W4 = (const float4*)W;
    float4* Ws4 = (float4*)Ws;
#pragma unroll
    for (int q = 0; q < 8; ++q)
        Ws4[q * 256 + tid] = W4[q * 256 + tid];

    const float4* h4 = (const float4*)h;
    float4* hs4 = (float4*)hs;
    const size_t hbase = (size_t)blockIdx.x * 512;
#pragma unroll
    for (int q = 0; q < 2; ++q)
        hs4[q * 256 + tid] = h4[hbase + q * 256 + tid];

    const float av1 = a[lane];
    const float av2 = a[F_OUT + lane];
    __syncthreads();

    float acc[4] = {0.f, 0.f, 0.f, 0.f};
    const int lr0 = w * 4;
    for (int k4 = 0; k4 < F_IN / 4; ++k4) {
        float4 hv[4];
#pragma unroll
        for (int rr = 0; rr < 4; ++rr)
            hv[rr] = hs4[(lr0 + rr) * (F_IN / 4) + k4];
#pragma unroll
        for (int kk = 0; kk < 4; ++kk) {
            float wv = Ws[(k4 * 4 + kk) * F_OUT + lane];
#pragma unroll
            for (int rr = 0; rr < 4; ++rr)
                acc[rr] += ((const float*)&hv[rr])[kk] * wv;
        }
    }

    const int b     = blockIdx.x >> 7;          // 128 blocks per batch
    const int j0    = (blockIdx.x & 127) * 16;  // node base within batch
    const size_t gr0 = (size_t)b * N + j0 + lr0;

#pragma unroll
    for (int rr = 0; rr < 4; ++rr) {
        t32[(lr0 + rr) * 65 + lane] = acc[rr];
        float fp = acc[rr] * av1;
        float gp = acc[rr] * av2;
#pragma unroll
        for (int off = 32; off >= 1; off >>= 1) {
            fp += __shfl_down(fp, off, 64);
            gp += __shfl_down(gp, off, 64);
        }
        if (lane == 0) {
            fv[gr0 + rr] = fp;
            gv[gr0 + rr] = gp;
        }
    }
    __syncthreads();

    const int f  = tid >> 2;
    const int jq = tid & 3;
    union { _Float16 h[4]; ushort4 u; } pk;
#pragma unroll
    for (int t = 0; t < 4; ++t)
        pk.h[t] = (_Float16)t32[(jq * 4 + t) * 65 + f];
    *(ushort4*)(WhT + (size_t)b * F_OUT * N + (size_t)f * N + j0 + jq * 4) = pk.u;
}

// ---------------------------------------------------------------------------
// Kernel 3: aggregation via MFMA with per-row max-shifted softmax.
// Block = (16 i's, batch b), 4 waves; wave w -> out[i0..15][16w..16w+15].
// ---------------------------------------------------------------------------
__global__ __launch_bounds__(256) void attn_mfma_kernel(
    const _Float16* __restrict__ WhT, const float* __restrict__ fv,
    const float* __restrict__ gv, const unsigned* __restrict__ bits,
    float* __restrict__ out)
{
    const int i0 = blockIdx.x * 16;
    const int b  = blockIdx.y;
    const int tid  = threadIdx.x;
    const int lane = tid & 63;
    const int wsl  = tid >> 6;     // wave = feature slice

    __shared__ float    gs[N];            // 8 KB
    __shared__ float    fs[16];
    __shared__ unsigned mws[16 * 64];     // 4 KB
    __shared__ _Float16 WhTs[64 * 40];    // rows padded to 40 f16
    __shared__ _Float16 Ps[16 * 40];
    __shared__ float    rs[16];
    __shared__ float    ms[16];

    // stage g row, f values, mask words
    const float4* g4 = (const float4*)(gv + (size_t)b * N);
    ((float4*)gs)[tid]       = g4[tid];
    ((float4*)gs)[tid + 256] = g4[tid + 256];
    if (tid < 16) fs[tid] = fv[(size_t)b * N + i0 + tid];
    ((uint4*)mws)[tid] = ((const uint4*)(bits + (size_t)(i0 + (tid >> 4)) * 64))[tid & 15];
    __syncthreads();

    const int ii = tid >> 4;        // i slot
    const int jj = tid & 15;        // part / j-group

    // --- per-row masked max of g: thread (ii, part=jj) scans j = jj*128..+128
    float gmax = -INFINITY;
#pragma unroll
    for (int t = 0; t < 4; ++t) {
        unsigned mw = mws[ii * 64 + jj * 4 + t];
        const int jb = jj * 128 + t * 32;
        while (mw) {
            int bit = __builtin_ctz(mw);
            gmax = fmaxf(gmax, gs[jb + bit]);
            mw &= mw - 1;
        }
    }
#pragma unroll
    for (int off = 8; off >= 1; off >>= 1)
        gmax = fmaxf(gmax, __shfl_down(gmax, off, 16));
    if (jj == 0) {
        float m = fs[ii] + gmax;           // leaky monotone: rowmax = leaky(fi+maxg)
        ms[ii] = (m > 0.f) ? m : ALPHA * m;
    }
    __syncthreads();

    const float fi = fs[ii];
    const float mi = ms[ii];
    const int fwh = tid >> 2;       // f row for WhT staging
    const int seg = tid & 3;
    const _Float16* whbase = WhT + (size_t)b * F_OUT * N + (size_t)fwh * N;

    const int mrow = lane & 15;
    const int quad = lane >> 4;

    f32x4 acc = {0.f, 0.f, 0.f, 0.f};
    float psum = 0.f;

    for (int kt = 0; kt < N / 32; ++kt) {
        const int j0 = kt * 32;
        float4 wv = *(const float4*)(whbase + j0 + seg * 8);

        // P tile: 2 values per thread, max-shifted
        int jA = j0 + jj * 2;
        float g0 = gs[jA], g1 = gs[jA + 1];
        unsigned mw = mws[ii * 64 + (j0 >> 5)];
        float s0 = fi + g0; s0 = (s0 > 0.f) ? s0 : ALPHA * s0;
        float s1 = fi + g1; s1 = (s1 > 0.f) ? s1 : ALPHA * s1;
        float p0 = ((mw >> (jj * 2)) & 1u)     ? __expf(s0 - mi) : 0.f;
        float p1 = ((mw >> (jj * 2 + 1)) & 1u) ? __expf(s1 - mi) : 0.f;
        half2v pk; pk[0] = (_Float16)p0; pk[1] = (_Float16)p1;
        psum += (float)pk[0] + (float)pk[1];   // denominator from rounded values
        *(half2v*)(&Ps[ii * 40 + jj * 2]) = pk;
        *(float4*)(&WhTs[fwh * 40 + seg * 8]) = wv;
        __syncthreads();

        half8 aF = *(const half8*)(&Ps[mrow * 40 + quad * 8]);
        half8 bF = *(const half8*)(&WhTs[(wsl * 16 + mrow) * 40 + quad * 8]);
        acc = __builtin_amdgcn_mfma_f32_16x16x32_f16(aF, bF, acc, 0, 0, 0);
        __syncthreads();
    }

    // row-sum reduce within 16-lane segments (threads sharing ii)
#pragma unroll
    for (int off = 8; off >= 1; off >>= 1)
        psum += __shfl_down(psum, off, 16);
    if (jj == 0) rs[ii] = psum;
    __syncthreads();

    // epilogue: D row = quad*4+reg, col = mrow
#pragma unroll
    for (int reg = 0; reg < 4; ++reg) {
        int irow = quad * 4 + reg;
        float v = acc[reg] / rs[irow];
        out[((size_t)b * N + i0 + irow) * F_OUT + wsl * 16 + mrow] = v;
    }
}

extern "C" void kernel_launch(void* const* d_in, const int* in_sizes, int n_in,
                              void* d_out, int out_size, void* d_ws, size_t ws_size,
                              hipStream_t stream) {
    const float* h   = (const float*)d_in[0];
    const float* adj = (const float*)d_in[1];
    const float* W   = (const float*)d_in[2];
    const float* a   = (const float*)d_in[3];
    float* out = (float*)d_out;

    char* ws = (char*)d_ws;
    _Float16* WhT = (_Float16*)ws;                        // 2 MB
    float* fv = (float*)(ws + (size_t)B * F_OUT * N * 2); // 64 KB
    float* gv = fv + (size_t)B * N;                       // 64 KB
    unsigned* bits = (unsigned*)(gv + (size_t)B * N);     // 512 KB

    bitmask_kernel<<<dim3(N), 256, 0, stream>>>(adj, bits);
    wh_fg_t_kernel<<<dim3(B * N / 16), 256, 0, stream>>>(h, W, a, WhT, fv, gv);
    attn_mfma_kernel<<<dim3(N / 16, B), 256, 0, stream>>>(WhT, fv, gv, bits, out);
}

// Round 5
// 132.243 us; speedup vs baseline: 1.6109x; 1.0128x over previous
//
#include <hip/hip_runtime.h>
#include <hip/hip_bf16.h>
#include <math.h>

#define B 8
#define N 2048
#define F_IN 128
#define F_OUT 64
#define ALPHA 0.2f

typedef _Float16 half8 __attribute__((ext_vector_type(8)));
typedef float f32x4 __attribute__((ext_vector_type(4)));

// ---------------------------------------------------------------------------
// Kernel 1: adj -> bitmask (u32 words). bits[i*64 + j/32] bit (j%32) = adj[i][j]>0
// ---------------------------------------------------------------------------
__global__ __launch_bounds__(256) void bitmask_kernel(
    const float* __restrict__ adj, unsigned* __restrict__ bits)
{
    const int i = blockIdx.x;
    const int tid = threadIdx.x;
    const int lane = tid & 63;
    const int w = tid >> 6;
    const float* row = adj + (size_t)i * N;
#pragma unroll
    for (int jt = 0; jt < 8; ++jt) {
        float v = row[jt * 256 + tid];
        unsigned long long m = __ballot(v > 0.f);
        if (lane == 0) {
            bits[i * 64 + jt * 8 + w * 2]     = (unsigned)m;
            bits[i * 64 + jt * 8 + w * 2 + 1] = (unsigned)(m >> 32);
        }
    }
}

// ---------------------------------------------------------------------------
// Kernel 2: WhT[b][f][j] (f16) = (h @ W)^T, plus f = Wh.a1, g = Wh.a2 (fp32)
// ---------------------------------------------------------------------------
__global__ __launch_bounds__(256) void wh_fg_t_kernel(
    const float* __restrict__ h, const float* __restrict__ W,
    const float* __restrict__ a, _Float16* __restrict__ WhT,
    float* __restrict__ fv, float* __restrict__ gv)
{
    const int tid  = threadIdx.x;
    const int w    = tid >> 6;
    const int lane = tid & 63;

    __shared__ float Ws[F_IN * F_OUT];    // 32 KB
    __shared__ float hs[16 * F_IN];       // 8 KB
    __shared__ float t32[16 * 65];        // transpose buffer (pad 65)

    const float4* W4 = (const float4*)W;
    float4* Ws4 = (float4*)Ws;
#pragma unroll
    for (int q = 0; q < 8; ++q)
        Ws4[q * 256 + tid] = W4[q * 256 + tid];

    const float4* h4 = (const float4*)h;
    float4* hs4 = (float4*)hs;
    const size_t hbase = (size_t)blockIdx.x * 512;
#pragma unroll
    for (int q = 0; q < 2; ++q)
        hs4[q * 256 + tid] = h4[hbase + q * 256 + tid];

    const float av1 = a[lane];
    const float av2 = a[F_OUT + lane];
    __syncthreads();

    float acc[4] = {0.f, 0.f, 0.f, 0.f};
    const int lr0 = w * 4;
    for (int k4 = 0; k4 < F_IN / 4; ++k4) {
        float4 hv[4];
#pragma unroll
        for (int rr = 0; rr < 4; ++rr)
            hv[rr] = hs4[(lr0 + rr) * (F_IN / 4) + k4];
#pragma unroll
        for (int kk = 0; kk < 4; ++kk) {
            float wv = Ws[(k4 * 4 + kk) * F_OUT + lane];
#pragma unroll
            for (int rr = 0; rr < 4; ++rr)
                acc[rr] += ((const float*)&hv[rr])[kk] * wv;
        }
    }

    const int b     = blockIdx.x >> 7;
    const int j0    = (blockIdx.x & 127) * 16;
    const size_t gr0 = (size_t)b * N + j0 + lr0;

#pragma unroll
    for (int rr = 0; rr < 4; ++rr) {
        t32[(lr0 + rr) * 65 + lane] = acc[rr];
        float fp = acc[rr] * av1;
        float gp = acc[rr] * av2;
#pragma unroll
        for (int off = 32; off >= 1; off >>= 1) {
            fp += __shfl_down(fp, off, 64);
            gp += __shfl_down(gp, off, 64);
        }
        if (lane == 0) {
            fv[gr0 + rr] = fp;
            gv[gr0 + rr] = gp;
        }
    }
    __syncthreads();

    const int f  = tid >> 2;
    const int jq = tid & 3;
    union { _Float16 h[4]; ushort4 u; } pk;
#pragma unroll
    for (int t = 0; t < 4; ++t)
        pk.h[t] = (_Float16)t32[(jq * 4 + t) * 65 + f];
    *(ushort4*)(WhT + (size_t)b * F_OUT * N + (size_t)f * N + j0 + jq * 4) = pk.u;
}

// ---------------------------------------------------------------------------
// Kernel 3: aggregation via MFMA, K=128 per barrier round (4 MFMA/wave/round).
// Block = (16 i's, batch b), 4 waves; wave w -> out[i0..15][16w..16w+15].
// ---------------------------------------------------------------------------
#define PSTR 136   // f16 row stride for Ps/WhTs (pad 128+8): uniform 8 lanes/bank

__global__ __launch_bounds__(256) void attn_mfma_kernel(
    const _Float16* __restrict__ WhT, const float* __restrict__ fv,
    const float* __restrict__ gv, const unsigned* __restrict__ bits,
    float* __restrict__ out)
{
    const int i0 = blockIdx.x * 16;
    const int b  = blockIdx.y;
    const int tid  = threadIdx.x;
    const int lane = tid & 63;
    const int wsl  = tid >> 6;     // wave = feature slice

    __shared__ float    gs[N];              // 8 KB
    __shared__ float    fs[16];
    __shared__ unsigned mws[16 * 64];       // 4 KB
    __shared__ _Float16 WhTs[64 * PSTR];    // 17 KB
    __shared__ _Float16 Ps[16 * PSTR];      // 4.25 KB
    __shared__ float    rs[16];
    __shared__ float    ms[16];

    // stage g row, f values, mask words
    const float4* g4 = (const float4*)(gv + (size_t)b * N);
    ((float4*)gs)[tid]       = g4[tid];
    ((float4*)gs)[tid + 256] = g4[tid + 256];
    if (tid < 16) fs[tid] = fv[(size_t)b * N + i0 + tid];
    ((uint4*)mws)[tid] = ((const uint4*)(bits + (size_t)(i0 + (tid >> 4)) * 64))[tid & 15];
    __syncthreads();

    const int ii = tid >> 4;        // i slot
    const int jj = tid & 15;        // j group

    // per-row masked max of g (leaky monotone => rowmax = leaky(fi + max g))
    float gmax = -INFINITY;
#pragma unroll
    for (int t = 0; t < 4; ++t) {
        unsigned mw = mws[ii * 64 + jj * 4 + t];
        const int jb = jj * 128 + t * 32;
        while (mw) {
            int bit = __builtin_ctz(mw);
            gmax = fmaxf(gmax, gs[jb + bit]);
            mw &= mw - 1;
        }
    }
#pragma unroll
    for (int off = 8; off >= 1; off >>= 1)
        gmax = fmaxf(gmax, __shfl_down(gmax, off, 16));
    if (jj == 0) {
        float m = fs[ii] + gmax;
        ms[ii] = (m > 0.f) ? m : ALPHA * m;
    }
    __syncthreads();

    const float fi = fs[ii];
    const float mi = ms[ii];
    const int fwh = tid >> 2;       // WhT row (feature) this thread stages
    const int seg = tid & 3;        // 32-f16 segment within row
    const _Float16* whbase = WhT + (size_t)b * F_OUT * N + (size_t)fwh * N;

    const int mrow = lane & 15;
    const int quad = lane >> 4;

    f32x4 acc = {0.f, 0.f, 0.f, 0.f};
    float psum = 0.f;

    for (int kt = 0; kt < N / 128; ++kt) {
        const int j0 = kt * 128;

        // global: stage 64x128 f16 slab (4 float4 per thread)
        float4 wv[4];
#pragma unroll
        for (int q = 0; q < 4; ++q)
            wv[q] = *(const float4*)(whbase + j0 + seg * 32 + q * 8);

        // P tile: 8 scores per thread (j = j0 + jj*8 .. +7)
        const int jA = j0 + jj * 8;
        unsigned mbits = (mws[ii * 64 + (j0 >> 5) + (jj >> 2)] >> ((jj & 3) * 8)) & 0xFFu;
        half8 pk;
#pragma unroll
        for (int t = 0; t < 8; ++t) {
            float s = fi + gs[jA + t];
            s = (s > 0.f) ? s : ALPHA * s;
            float p = ((mbits >> t) & 1u) ? __expf(s - mi) : 0.f;
            pk[t] = (_Float16)p;
            psum += (float)pk[t];
        }
        *(half8*)(&Ps[ii * PSTR + jj * 8]) = pk;
#pragma unroll
        for (int q = 0; q < 4; ++q)
            *(float4*)(&WhTs[fwh * PSTR + seg * 32 + q * 8]) = wv[q];
        __syncthreads();

#pragma unroll
        for (int q = 0; q < 4; ++q) {
            half8 aF = *(const half8*)(&Ps[mrow * PSTR + q * 32 + quad * 8]);
            half8 bF = *(const half8*)(&WhTs[(wsl * 16 + mrow) * PSTR + q * 32 + quad * 8]);
            acc = __builtin_amdgcn_mfma_f32_16x16x32_f16(aF, bF, acc, 0, 0, 0);
        }
        __syncthreads();
    }

    // denominator: reduce psum over the 16 threads sharing ii
#pragma unroll
    for (int off = 8; off >= 1; off >>= 1)
        psum += __shfl_down(psum, off, 16);
    if (jj == 0) rs[ii] = psum;
    __syncthreads();

    // epilogue: D row = quad*4+reg, col = mrow
#pragma unroll
    for (int reg = 0; reg < 4; ++reg) {
        int irow = quad * 4 + reg;
        float v = acc[reg] / rs[irow];
        out[((size_t)b * N + i0 + irow) * F_OUT + wsl * 16 + mrow] = v;
    }
}

extern "C" void kernel_launch(void* const* d_in, const int* in_sizes, int n_in,
                              void* d_out, int out_size, void* d_ws, size_t ws_size,
                              hipStream_t stream) {
    const float* h   = (const float*)d_in[0];
    const float* adj = (const float*)d_in[1];
    const float* W   = (const float*)d_in[2];
    const float* a   = (const float*)d_in[3];
    float* out = (float*)d_out;

    char* ws = (char*)d_ws;
    _Float16* WhT = (_Float16*)ws;                        // 2 MB
    float* fv = (float*)(ws + (size_t)B * F_OUT * N * 2); // 64 KB
    float* gv = fv + (size_t)B * N;                       // 64 KB
    unsigned* bits = (unsigned*)(gv + (size_t)B * N);     // 512 KB

    bitmask_kernel<<<dim3(N), 256, 0, stream>>>(adj, bits);
    wh_fg_t_kernel<<<dim3(B * N / 16), 256, 0, stream>>>(h, W, a, WhT, fv, gv);
    attn_mfma_kernel<<<dim3(N / 16, B), 256, 0, stream>>>(WhT, fv, gv, bits, out);
}